// Round 7
// baseline (471.419 us; speedup 1.0000x reference)
//
#include <hip/hip_runtime.h>
#include <math.h>

#define NBV 4096
#define KNE 64
#define RPB 4            // rows per persistent block
#define NBLK (NBV/RPB)   // 1024 blocks
// flat float offsets in d_out: (d, dist, pos, idx) in return order
#define D_OFF    0
#define DIST_OFF (NBV*KNE)                       // 262144
#define POS_OFF  (DIST_OFF + NBV*KNE*400)        // 105119744
#define IDX_OFF  (POS_OFF + NBV*KNE*16)          // 109314048

// ws layout (floats): [0, 65536) crd5 rows, stride 16 (5 pts x 3 + pad)
//                     [65536, 81920) compact CA as float4 (stride 4)
#define WS_CRD5 0
#define WS_CA4  (NBV*16)
#define WS_FLOATS (NBV*16 + NBV*4)

typedef float f4v __attribute__((ext_vector_type(4)));

// float -> order-preserving uint32 (ascending float => ascending uint)
__device__ __forceinline__ unsigned int f2sort(float f) {
  unsigned int u = __float_as_uint(f);
  return (u & 0x80000000u) ? ~u : (u | 0x80000000u);
}
__device__ __forceinline__ float sort2f(unsigned int s) {
  unsigned int u = (s & 0x80000000u) ? (s & 0x7FFFFFFFu) : ~s;
  return __uint_as_float(u);
}

// q-th float4 (q in 0..3) of the 16-float crd5 row r, computed from raw crd
__device__ __forceinline__ float4 crd5_f4(const float* __restrict__ crd, int r,
                                          int q) {
  if (q < 3) return ((const float4*)crd)[r * 3 + q];
  const float4 a = ((const float4*)crd)[r * 3 + 0];
  const float4 b = ((const float4*)crd)[r * 3 + 1];
  const float4 c = ((const float4*)crd)[r * 3 + 2];
  const float bx = a.w - a.x, by = b.x - a.y, bz = b.y - a.z;   // p1-p0
  const float cx = b.z - a.w, cy = b.w - b.x, cz = c.x - b.y;   // p2-p1
  const float axv = by * cz - bz * cy;
  const float ayv = bz * cx - bx * cz;
  const float azv = bx * cy - by * cx;
  return make_float4(
      -0.58273431f * axv + 0.56802827f * bx - 0.54067466f * cx + a.w,
      -0.58273431f * ayv + 0.56802827f * by - 0.54067466f * cy + b.x,
      -0.58273431f * azv + 0.56802827f * bz - 0.54067466f * cz + b.y, 0.0f);
}

// ---------------- prep: crd -> compact crd5 (stride 16) + CA float4 --------
__global__ __launch_bounds__(256) void prep_k(const float* __restrict__ crd,
                                              float* __restrict__ ws) {
  const int r = blockIdx.x * 256 + threadIdx.x;  // 4096 threads
  const float4 a = ((const float4*)crd)[r * 3 + 0];
  const float4 b = ((const float4*)crd)[r * 3 + 1];
  const float4 c = ((const float4*)crd)[r * 3 + 2];
  const float bx = a.w - a.x, by = b.x - a.y, bz = b.y - a.z;
  const float cx = b.z - a.w, cy = b.w - b.x, cz = c.x - b.y;
  const float axv = by * cz - bz * cy;
  const float ayv = bz * cx - bx * cz;
  const float azv = bx * cy - by * cx;
  const float cbx = -0.58273431f * axv + 0.56802827f * bx - 0.54067466f * cx + a.w;
  const float cby = -0.58273431f * ayv + 0.56802827f * by - 0.54067466f * cy + b.x;
  const float cbz = -0.58273431f * azv + 0.56802827f * bz - 0.54067466f * cz + b.y;

  float4* row = (float4*)(ws + WS_CRD5 + r * 16);
  row[0] = a;
  row[1] = b;
  row[2] = c;
  row[3] = make_float4(cbx, cby, cbz, 0.0f);
  ((float4*)(ws + WS_CA4))[r] = make_float4(a.w, b.x, b.y, 0.0f);
}

// -------- persistent pipelined kernel: 4 rows/block, scan(r+1) in grbf(r) ---
// Per-row semantics identical to the r4-verified kernel. The 4096-point scan
// + histogram of the NEXT row is interleaved into the GRBF store loop of the
// CURRENT row (both barrier-free, disjoint LDS) so dist stores issue
// continuously instead of in per-cohort bursts.
__global__ __launch_bounds__(256) void fused_p(const float* __restrict__ ws,
                                               float* __restrict__ out) {
  const int t = threadIdx.x;
  const int lane = t & 63, wid = t >> 6;
  const unsigned long long lmask = (1ull << lane) - 1ull;

  __shared__ unsigned int hist[2048];        // 8 KB (live during grbf of prev)
  __shared__ unsigned long long cand[512];   // 4 KB
  __shared__ float rowsd[2640];              // rows[0,1040)+dvals[1040,2640)
  __shared__ int jidx[64];
  __shared__ unsigned int cnt;
  __shared__ int selbin;
  __shared__ unsigned int wsum[4];

  float* rows = rowsd;
  float* dvals = rowsd + 1040;

  // ---- init: zero hist, standalone scan of row 0 ----
  for (int b = t; b < 2048; b += 256) hist[b] = 0u;
  __syncthreads();

  float dv[16];
  {
    const int i = blockIdx.x;
    const float4 ci = ((const float4*)(ws + WS_CA4))[i];
#pragma unroll
    for (int s = 0; s < 16; s++) {
      const int j = t + 256 * s;
      const float4 cj = ((const float4*)(ws + WS_CA4))[j];
      const float dx = ci.x - cj.x, dy = ci.y - cj.y, dz = ci.z - cj.z;
      float f = sqrtf(dx * dx + dy * dy + dz * dz);
      if (j == i) f = -1.0f;  // diag = -1 => self is always rank 0
      dv[s] = f;
      int b = (int)(f * 16.0f);
      b = b < 0 ? 0 : (b > 2047 ? 2047 : b);
      atomicAdd(&hist[b], 1u);
    }
  }

  for (int rr = 0; rr < RPB; rr++) {
    const int i = blockIdx.x + NBLK * rr;
    __syncthreads();  // hist atomics of this row done; grbf reads of prev done

    // ---- prefix over 2048 bins; first bin with cum >= 64 ----
    unsigned int bc[8];
    unsigned int loc = 0;
#pragma unroll
    for (int r = 0; r < 8; r++) { bc[r] = hist[t * 8 + r]; loc += bc[r]; }
    unsigned int x = loc;
#pragma unroll
    for (int off = 1; off < 64; off <<= 1) {
      unsigned int y = __shfl_up(x, off, 64);
      if (lane >= off) x += y;
    }
    if (lane == 63) wsum[wid] = x;
    if (t == 0) cnt = 0u;
    __syncthreads();
    unsigned int woff = 0;
#pragma unroll
    for (int w = 0; w < 4; w++)
      if (w < wid) woff += wsum[w];
    unsigned int cum = woff + x - loc;
#pragma unroll
    for (int r = 0; r < 8; r++) {
      if (cum < 64u && cum + bc[r] >= 64u) selbin = t * 8 + r;  // unique
      cum += bc[r];
    }
    __syncthreads();
    const int B = selbin;

    // ---- collect candidates in bins <= B (ballot-compacted) ----
#pragma unroll
    for (int s = 0; s < 16; s++) {
      const float f = dv[s];
      int b = (int)(f * 16.0f);
      b = b < 0 ? 0 : (b > 2047 ? 2047 : b);
      const bool pred = (b <= B);
      const unsigned long long mask = __ballot(pred);
      unsigned int base = 0;
      if (lane == 0 && mask)
        base = atomicAdd(&cnt, (unsigned int)__popcll(mask));
      base = __shfl(base, 0, 64);
      if (pred) {
        const unsigned int p = base + (unsigned int)__popcll(mask & lmask);
        if (p < 512u) {
          const int j = t + 256 * s;
          cand[p] = (((unsigned long long)f2sort(f)) << 32) | (unsigned int)j;
        }
      }
    }
    __syncthreads();

    // ---- O(M^2) rank-select: winner r gets the (r+1)-smallest key ----
    {
      unsigned int M = cnt;
      if (M > 512u) M = 512u;
      for (int p = t; p < (int)M; p += 256) {
        const unsigned long long key = cand[p];
        int r = 0;
        for (int q = 0; q < (int)M; q++) r += (cand[q] < key);
        if (r < KNE) {
          const int j = (int)(unsigned int)(key & 0xFFFFFFFFull);
          const float f = sort2f((unsigned int)(key >> 32));
          jidx[r] = j;
          out[D_OFF + (size_t)i * KNE + r] = (r == 0) ? 0.0f : f;  // d[:,0]=0
          out[IDX_OFF + (size_t)i * KNE + r] = (float)j;
        }
      }
    }
    // zero hist for the next row's scan (hist is dead after prefix)
    for (int b = t; b < 2048; b += 256) hist[b] = 0u;
    __syncthreads();  // jidx + zeroed hist visible

    // ---- stage rows (loads issued first) + pos with all 256 threads ----
    const int sr = t >> 2, qq = t & 3;
    float4 v = ((const float4*)ws)[jidx[sr] * 4 + qq];
    float4 v2;
    if (t < 4) v2 = ((const float4*)ws)[i * 4 + t];

    {
      const int n = sr, g = qq;
      const int j = jidx[n];
      int di = i - j;
      if (di < 0) di = -di;
      const float offv = (float)di;
      const bool hi = (g & 1);
      const float fA = hi ? 0.01f                   : 1.0f;
      const float fB = hi ? 0.0031622776601683794f  : 0.31622776601683794f;
      const float fC = hi ? 0.001f                  : 0.1f;
      const float fD = hi ? 0.00031622776601683794f : 0.031622776601683791f;
      float s0, c0, s1, c1, s2, c2, s3, c3;
      sincosf(offv * fA, &s0, &c0);
      sincosf(offv * fB, &s1, &c1);
      sincosf(offv * fC, &s2, &c2);
      sincosf(offv * fD, &s3, &c3);
      f4v o;
      if (g < 2) o = (f4v){c0, c1, c2, c3};
      else       o = (f4v){s0, s1, s2, s3};
      f4v* pv = (f4v*)(out + POS_OFF) + ((size_t)i * KNE + n) * 4 + g;
      __builtin_nontemporal_store(o, pv);
    }

    ((float4*)rows)[sr * 4 + qq] = v;
    if (t < 4) ((float4*)rows)[64 * 4 + t] = v2;
    __syncthreads();  // rows ready

    // ---- 1600 pair distances into LDS ----
#pragma unroll
    for (int it = 0; it < 7; it++) {
      const int pid = t + 256 * it;
      if (pid < 1600) {
        const int k = pid / 25;
        const int p = pid - k * 25;
        const int p0 = p / 5;
        const int p1 = p - p0 * 5;
        const float dx = rows[64 * 16 + p0 * 3 + 0] - rows[k * 16 + p1 * 3 + 0];
        const float dy = rows[64 * 16 + p0 * 3 + 1] - rows[k * 16 + p1 * 3 + 1];
        const float dz = rows[64 * 16 + p0 * 3 + 2] - rows[k * 16 + p1 * 3 + 2];
        dvals[pid] = sqrtf(dx * dx + dy * dy + dz * dz);
      }
    }
    __syncthreads();  // dvals ready

    // ---- GRBF(cur) stores interleaved with SCAN(next) ----
    const bool nxt = (rr + 1 < RPB);
    const int inext = blockIdx.x + NBLK * (rr + 1);
    float4 cin = make_float4(0.0f, 0.0f, 0.0f, 0.0f);
    if (nxt) cin = ((const float4*)(ws + WS_CA4))[inext];
    const float step = 20.0f / 15.0f;
    const float TWO_S = 2.6666667f;   // 2*step
    const float S2 = 1.7777778f;      // step^2
    const float RHO = 0.02856550f;    // exp(-2*step^2)
    f4v* dst = (f4v*)(out + DIST_OFF) + (size_t)i * 6400;
#pragma unroll
    for (int s = 0; s < 25; s++) {
      const int f4i = t + 256 * s;  // 6400 float4 per row
      const int pair = f4i >> 2;
      const float cb0 = (float)((f4i & 3) * 4) * step;
      float u = dvals[pair] - cb0;
      u = fminf(u, 16.0f);
      float e = __expf(-u * u);
      float q = __expf(fmaf(TWO_S, u, -S2));
      f4v o;
      o.x = e;
      e *= q;           o.y = e;
      q *= RHO; e *= q; o.z = e;
      q *= RHO; e *= q; o.w = e;
      __builtin_nontemporal_store(o, dst + f4i);
      if (nxt && s < 16) {  // next row's distance scan rides the store stream
        const int j = t + 256 * s;
        const float4 cj = ((const float4*)(ws + WS_CA4))[j];
        const float dx = cin.x - cj.x, dy = cin.y - cj.y, dz = cin.z - cj.z;
        float f = sqrtf(dx * dx + dy * dy + dz * dz);
        if (j == inext) f = -1.0f;
        dv[s] = f;
        int b = (int)(f * 16.0f);
        b = b < 0 ? 0 : (b > 2047 ? 2047 : b);
        atomicAdd(&hist[b], 1u);
      }
    }
  }
}

// ---------------- fallback: block-per-row fused kernel (no ws) -------------
__global__ __launch_bounds__(256) void fused_k(const float* __restrict__ crd,
                                               float* __restrict__ out) {
  const int i = blockIdx.x;
  const int t = threadIdx.x;

  __shared__ float region0[2688];
  __shared__ unsigned long long cand[512];
  __shared__ int jidx[64];
  __shared__ unsigned int cnt;
  __shared__ int selbin;
  __shared__ unsigned int wsum[4];

  unsigned int* hist = (unsigned int*)region0;
  float* rows = region0;
  float* dvals = region0 + 1040;

  for (int b = t; b < 2048; b += 256) hist[b] = 0u;
  if (t == 0) cnt = 0u;
  __syncthreads();

  const float cax = crd[i * 12 + 3], cay = crd[i * 12 + 4],
              caz = crd[i * 12 + 5];

  float dv[16];
#pragma unroll
  for (int s = 0; s < 16; s++) {
    const int j = t + 256 * s;
    const float dx = cax - crd[j * 12 + 3], dy = cay - crd[j * 12 + 4],
                dz = caz - crd[j * 12 + 5];
    float f = sqrtf(dx * dx + dy * dy + dz * dz);
    if (j == i) f = -1.0f;
    dv[s] = f;
    int b = (int)(f * 16.0f);
    b = b < 0 ? 0 : (b > 2047 ? 2047 : b);
    atomicAdd(&hist[b], 1u);
  }
  __syncthreads();

  unsigned int bc[8];
  unsigned int loc = 0;
#pragma unroll
  for (int r = 0; r < 8; r++) { bc[r] = hist[t * 8 + r]; loc += bc[r]; }
  const int lane = t & 63, wid = t >> 6;
  unsigned int x = loc;
#pragma unroll
  for (int off = 1; off < 64; off <<= 1) {
    unsigned int y = __shfl_up(x, off, 64);
    if (lane >= off) x += y;
  }
  if (lane == 63) wsum[wid] = x;
  __syncthreads();
  unsigned int woff = 0;
#pragma unroll
  for (int w = 0; w < 4; w++)
    if (w < wid) woff += wsum[w];
  unsigned int c = woff + x - loc;
#pragma unroll
  for (int r = 0; r < 8; r++) {
    if (c < 64u && c + bc[r] >= 64u) selbin = t * 8 + r;
    c += bc[r];
  }
  __syncthreads();
  const int B = selbin;

  const unsigned long long lmask = (1ull << lane) - 1ull;
#pragma unroll
  for (int s = 0; s < 16; s++) {
    const float f = dv[s];
    int b = (int)(f * 16.0f);
    b = b < 0 ? 0 : (b > 2047 ? 2047 : b);
    const bool pred = (b <= B);
    const unsigned long long mask = __ballot(pred);
    unsigned int base = 0;
    if (lane == 0 && mask)
      base = atomicAdd(&cnt, (unsigned int)__popcll(mask));
    base = __shfl(base, 0, 64);
    if (pred) {
      const unsigned int pp = base + (unsigned int)__popcll(mask & lmask);
      if (pp < 512u) {
        const int j = t + 256 * s;
        cand[pp] = (((unsigned long long)f2sort(f)) << 32) | (unsigned int)j;
      }
    }
  }
  __syncthreads();

  {
    unsigned int M = cnt;
    if (M > 512u) M = 512u;
    for (int pi = t; pi < (int)M; pi += 256) {
      const unsigned long long key = cand[pi];
      int r = 0;
      for (int q = 0; q < (int)M; q++) r += (cand[q] < key);
      if (r < KNE) {
        const int j = (int)(unsigned int)(key & 0xFFFFFFFFull);
        const float f = sort2f((unsigned int)(key >> 32));
        jidx[r] = j;
        out[D_OFF + i * KNE + r] = (r == 0) ? 0.0f : f;
        out[IDX_OFF + i * KNE + r] = (float)j;
      }
    }
  }
  __syncthreads();

  const int sr = t >> 2, qq = t & 3;
  float4 v, v2;
  v = crd5_f4(crd, jidx[sr], qq);
  if (t < 4) v2 = crd5_f4(crd, i, t);

  {
    const int n = sr, g = qq;
    const int j = jidx[n];
    int di = i - j;
    if (di < 0) di = -di;
    const float offv = (float)di;
    const bool hi = (g & 1);
    const float fA = hi ? 0.01f                   : 1.0f;
    const float fB = hi ? 0.0031622776601683794f  : 0.31622776601683794f;
    const float fC = hi ? 0.001f                  : 0.1f;
    const float fD = hi ? 0.00031622776601683794f : 0.031622776601683791f;
    float s0, c0, s1, c1, s2, c2, s3, c3;
    sincosf(offv * fA, &s0, &c0);
    sincosf(offv * fB, &s1, &c1);
    sincosf(offv * fC, &s2, &c2);
    sincosf(offv * fD, &s3, &c3);
    f4v o;
    if (g < 2) o = (f4v){c0, c1, c2, c3};
    else       o = (f4v){s0, s1, s2, s3};
    f4v* pv = (f4v*)(out + POS_OFF) + (size_t)(i * KNE + n) * 4 + g;
    __builtin_nontemporal_store(o, pv);
  }

  ((float4*)rows)[sr * 4 + qq] = v;
  if (t < 4) ((float4*)rows)[64 * 4 + t] = v2;
  __syncthreads();

#pragma unroll
  for (int it = 0; it < 7; it++) {
    const int pid = t + 256 * it;
    if (pid < 1600) {
      const int k = pid / 25;
      const int p = pid - k * 25;
      const int p0 = p / 5;
      const int p1 = p - p0 * 5;
      const float dx = rows[64 * 16 + p0 * 3 + 0] - rows[k * 16 + p1 * 3 + 0];
      const float dy = rows[64 * 16 + p0 * 3 + 1] - rows[k * 16 + p1 * 3 + 1];
      const float dz = rows[64 * 16 + p0 * 3 + 2] - rows[k * 16 + p1 * 3 + 2];
      dvals[pid] = sqrtf(dx * dx + dy * dy + dz * dz);
    }
  }
  __syncthreads();

  const float step = 20.0f / 15.0f;
  const float TWO_S = 2.6666667f;
  const float S2 = 1.7777778f;
  const float RHO = 0.02856550f;
  f4v* dst = (f4v*)(out + DIST_OFF) + (size_t)i * 6400;
#pragma unroll
  for (int s = 0; s < 25; s++) {
    const int f4i = t + 256 * s;
    const int pair = f4i >> 2;
    const float cb0 = (float)((f4i & 3) * 4) * step;
    float u = dvals[pair] - cb0;
    u = fminf(u, 16.0f);
    float e = __expf(-u * u);
    float q = __expf(fmaf(TWO_S, u, -S2));
    f4v o;
    o.x = e;
    e *= q;           o.y = e;
    q *= RHO; e *= q; o.z = e;
    q *= RHO; e *= q; o.w = e;
    __builtin_nontemporal_store(o, dst + f4i);
  }
}

extern "C" void kernel_launch(void* const* d_in, const int* in_sizes, int n_in,
                              void* d_out, int out_size, void* d_ws, size_t ws_size,
                              hipStream_t stream) {
  const float* crd = (const float*)d_in[0];
  float* out = (float*)d_out;
  if (ws_size >= (size_t)WS_FLOATS * sizeof(float)) {
    float* ws = (float*)d_ws;
    hipLaunchKernelGGL(prep_k, dim3(NBV / 256), dim3(256), 0, stream, crd, ws);
    hipLaunchKernelGGL(fused_p, dim3(NBLK), dim3(256), 0, stream, ws, out);
  } else {
    hipLaunchKernelGGL(fused_k, dim3(NBV), dim3(256), 0, stream, crd, out);
  }
}

// Round 10
// 446.857 us; speedup vs baseline: 1.0550x; 1.0550x over previous
//
#include <hip/hip_runtime.h>
#include <math.h>

#define NBV 4096
#define KNE 64
// flat float offsets in d_out: (d, dist, pos, idx) in return order
#define D_OFF    0
#define DIST_OFF (NBV*KNE)                       // 262144
#define POS_OFF  (DIST_OFF + NBV*KNE*400)        // 105119744
#define IDX_OFF  (POS_OFF + NBV*KNE*16)          // 109314048

typedef float f4v __attribute__((ext_vector_type(4)));

// float -> order-preserving uint32 (ascending float => ascending uint)
__device__ __forceinline__ unsigned int f2sort(float f) {
  unsigned int u = __float_as_uint(f);
  return (u & 0x80000000u) ? ~u : (u | 0x80000000u);
}
__device__ __forceinline__ float sort2f(unsigned int s) {
  unsigned int u = (s & 0x80000000u) ? (s & 0x7FFFFFFFu) : ~s;
  return __uint_as_float(u);
}

// q-th float4 (q in 0..3) of the 16-float crd5 row r, computed from raw crd.
// Row r of crd occupies floats [12r,12r+12) = 3 float4s; q=3 synthesizes Cb.
__device__ __forceinline__ float4 crd5_f4(const float* __restrict__ crd, int r,
                                          int q) {
  if (q < 3) return ((const float4*)crd)[r * 3 + q];
  const float4 a = ((const float4*)crd)[r * 3 + 0];
  const float4 b = ((const float4*)crd)[r * 3 + 1];
  const float4 c = ((const float4*)crd)[r * 3 + 2];
  const float bx = a.w - a.x, by = b.x - a.y, bz = b.y - a.z;   // p1-p0
  const float cx = b.z - a.w, cy = b.w - b.x, cz = c.x - b.y;   // p2-p1
  const float axv = by * cz - bz * cy;
  const float ayv = bz * cx - bx * cz;
  const float azv = bx * cy - by * cx;
  return make_float4(
      -0.58273431f * axv + 0.56802827f * bx - 0.54067466f * cx + a.w,
      -0.58273431f * ayv + 0.56802827f * by - 0.54067466f * cy + b.x,
      -0.58273431f * azv + 0.56802827f * bz - 0.54067466f * cz + b.y, 0.0f);
}

// ---------------- single fused kernel: r4 semantics, no prep launch --------
// Selection: histogram-bin threshold -> ballot-compacted collect -> O(M^2)
// rank-select. Scan reads CA (= crd[:,1]) directly from crd (L2-resident);
// stage phase computes crd5 rows inline via crd5_f4. GRBF store loop wrapped
// in s_setprio(1) (T5): store-phase waves get CU priority over scan-phase
// waves of other resident blocks, keeping the HBM write pipe fed.
__global__ __launch_bounds__(256) void fused_k(const float* __restrict__ crd,
                                               float* __restrict__ out) {
  const int i = blockIdx.x;
  const int t = threadIdx.x;

  // region0 union: selection uses it as hist[2048] (8 KB);
  // dist phase reuses it as rows[65*16] (4160 B) + dvals[1600] (6400 B).
  __shared__ float region0[2688];          // 10752 B
  __shared__ unsigned long long cand[512]; // 4 KB
  __shared__ int jidx[64];
  __shared__ unsigned int cnt;
  __shared__ int selbin;
  __shared__ unsigned int wsum[4];

  unsigned int* hist = (unsigned int*)region0;
  float* rows = region0;          // [0, 1040)
  float* dvals = region0 + 1040;  // [1040, 2640)

  for (int b = t; b < 2048; b += 256) hist[b] = 0u;
  if (t == 0) cnt = 0u;
  __syncthreads();

  const float cax = crd[i * 12 + 3], cay = crd[i * 12 + 4],
              caz = crd[i * 12 + 5];

  // ---- distance scan + histogram (bins of 1/16 over [0,128)) ----
  float dv[16];
#pragma unroll
  for (int s = 0; s < 16; s++) {
    const int j = t + 256 * s;
    const float dx = cax - crd[j * 12 + 3], dy = cay - crd[j * 12 + 4],
                dz = caz - crd[j * 12 + 5];
    float f = sqrtf(dx * dx + dy * dy + dz * dz);
    if (j == i) f = -1.0f;  // diag = -1 => self is always rank 0
    dv[s] = f;
    int b = (int)(f * 16.0f);
    b = b < 0 ? 0 : (b > 2047 ? 2047 : b);
    atomicAdd(&hist[b], 1u);
  }
  __syncthreads();

  // ---- block prefix scan over 2048 bins; first bin with cum >= 64 ----
  unsigned int bc[8];
  unsigned int loc = 0;
#pragma unroll
  for (int r = 0; r < 8; r++) { bc[r] = hist[t * 8 + r]; loc += bc[r]; }
  const int lane = t & 63, wid = t >> 6;
  unsigned int x = loc;
#pragma unroll
  for (int off = 1; off < 64; off <<= 1) {
    unsigned int y = __shfl_up(x, off, 64);
    if (lane >= off) x += y;
  }
  if (lane == 63) wsum[wid] = x;
  __syncthreads();
  unsigned int woff = 0;
#pragma unroll
  for (int w = 0; w < 4; w++)
    if (w < wid) woff += wsum[w];
  unsigned int c = woff + x - loc;
#pragma unroll
  for (int r = 0; r < 8; r++) {
    if (c < 64u && c + bc[r] >= 64u) selbin = t * 8 + r;  // unique crossing
    c += bc[r];
  }
  __syncthreads();
  const int B = selbin;

  // ---- collect candidates in bins <= B (ballot-compacted, cap 512) ----
  const unsigned long long lmask = (1ull << lane) - 1ull;
#pragma unroll
  for (int s = 0; s < 16; s++) {
    const float f = dv[s];
    int b = (int)(f * 16.0f);
    b = b < 0 ? 0 : (b > 2047 ? 2047 : b);
    const bool pred = (b <= B);
    const unsigned long long mask = __ballot(pred);
    unsigned int base = 0;
    if (lane == 0 && mask)
      base = atomicAdd(&cnt, (unsigned int)__popcll(mask));
    base = __shfl(base, 0, 64);
    if (pred) {
      const unsigned int p = base + (unsigned int)__popcll(mask & lmask);
      if (p < 512u) {
        const int j = t + 256 * s;
        cand[p] = (((unsigned long long)f2sort(f)) << 32) | (unsigned int)j;
      }
    }
  }
  __syncthreads();

  // ---- O(M^2) rank-select: winner r gets the (r+1)-smallest key ----
  {
    unsigned int M = cnt;
    if (M > 512u) M = 512u;
    for (int p = t; p < (int)M; p += 256) {
      const unsigned long long key = cand[p];
      int r = 0;
      for (int q = 0; q < (int)M; q++) r += (cand[q] < key);  // LDS broadcast
      if (r < KNE) {
        const int j = (int)(unsigned int)(key & 0xFFFFFFFFull);
        const float f = sort2f((unsigned int)(key >> 32));
        jidx[r] = j;
        out[D_OFF + i * KNE + r] = (r == 0) ? 0.0f : f;  // d[:,0] = 0
        out[IDX_OFF + i * KNE + r] = (float)j;
      }
    }
  }
  __syncthreads();  // jidx ready; hist region dead -> reuse as rows/dvals

  // ---- stage 65 crd5 rows (loads issued first) + pos, all 256 threads ----
  const int sr = t >> 2, qq = t & 3;
  float4 v = crd5_f4(crd, jidx[sr], qq);
  float4 v2;
  if (t < 4) v2 = crd5_f4(crd, i, t);

  // pos: thread (n,g) = (t>>2, t&3) computes one float4 of neighbor n:
  //   g=0: cos(f0..f3)  g=1: cos(f4..f7)  g=2: sin(f0..f3)  g=3: sin(f4..f7)
  {
    const int n = sr, g = qq;
    const int j = jidx[n];
    int di = i - j;
    if (di < 0) di = -di;
    const float offv = (float)di;
    const bool hi = (g & 1);
    const float fA = hi ? 0.01f                   : 1.0f;
    const float fB = hi ? 0.0031622776601683794f  : 0.31622776601683794f;
    const float fC = hi ? 0.001f                  : 0.1f;
    const float fD = hi ? 0.00031622776601683794f : 0.031622776601683791f;
    float s0, c0, s1, c1, s2, c2, s3, c3;
    sincosf(offv * fA, &s0, &c0);
    sincosf(offv * fB, &s1, &c1);
    sincosf(offv * fC, &s2, &c2);
    sincosf(offv * fD, &s3, &c3);
    f4v o;
    if (g < 2) o = (f4v){c0, c1, c2, c3};
    else       o = (f4v){s0, s1, s2, s3};
    f4v* pv = (f4v*)(out + POS_OFF) + (size_t)(i * KNE + n) * 4 + g;
    __builtin_nontemporal_store(o, pv);
  }

  ((float4*)rows)[sr * 4 + qq] = v;
  if (t < 4) ((float4*)rows)[64 * 4 + t] = v2;
  __syncthreads();

  // ---- 1600 pair distances into LDS ----
#pragma unroll
  for (int it = 0; it < 7; it++) {
    const int pid = t + 256 * it;
    if (pid < 1600) {
      const int k = pid / 25;
      const int p = pid - k * 25;
      const int p0 = p / 5;
      const int p1 = p - p0 * 5;
      const float dx = rows[64 * 16 + p0 * 3 + 0] - rows[k * 16 + p1 * 3 + 0];
      const float dy = rows[64 * 16 + p0 * 3 + 1] - rows[k * 16 + p1 * 3 + 1];
      const float dz = rows[64 * 16 + p0 * 3 + 2] - rows[k * 16 + p1 * 3 + 2];
      dvals[pid] = sqrtf(dx * dx + dy * dy + dz * dz);
    }
  }
  __syncthreads();

  // ---- GRBF encode (exp-recurrence) + NT stores, setprio(1)-wrapped ----
  // E_{k+1} = E_k * q_k, q_{k+1} = q_k * rho, q_0 = exp(2s*u - s^2),
  // rho = exp(-2 s^2). u clamped at 16 keeps q finite (true values there
  // underflow to 0). 2 exps + 5 muls per float4 instead of 4 exps.
  const float step = 20.0f / 15.0f;        // linspace(0,20,16) spacing
  const float TWO_S = 2.6666667f;          // 2*step
  const float S2 = 1.7777778f;             // step^2
  const float RHO = 0.02856550f;           // exp(-2*step^2)
  f4v* dst = (f4v*)(out + DIST_OFF) + (size_t)i * 6400;
  __builtin_amdgcn_s_setprio(1);  // T5: favor store-phase waves on the CU
#pragma unroll
  for (int s = 0; s < 25; s++) {
    const int f4i = t + 256 * s;  // 6400 float4 per block
    const int pair = f4i >> 2;
    const float cb0 = (float)((f4i & 3) * 4) * step;
    float u = dvals[pair] - cb0;
    u = fminf(u, 16.0f);
    float e = __expf(-u * u);
    float q = __expf(fmaf(TWO_S, u, -S2));
    f4v o;
    o.x = e;
    e *= q;           o.y = e;
    q *= RHO; e *= q; o.z = e;
    q *= RHO; e *= q; o.w = e;
    __builtin_nontemporal_store(o, dst + f4i);
  }
  __builtin_amdgcn_s_setprio(0);
}

extern "C" void kernel_launch(void* const* d_in, const int* in_sizes, int n_in,
                              void* d_out, int out_size, void* d_ws, size_t ws_size,
                              hipStream_t stream) {
  const float* crd = (const float*)d_in[0];
  float* out = (float*)d_out;
  hipLaunchKernelGGL(fused_k, dim3(NBV), dim3(256), 0, stream, crd, out);
}